// Round 1
// baseline (651.552 us; speedup 1.0000x reference)
//
#include <hip/hip_runtime.h>

typedef unsigned short u16;
typedef unsigned int u32;
typedef float f32x4 __attribute__((ext_vector_type(4)));
typedef __bf16 bf16x8 __attribute__((ext_vector_type(8)));

#define DEV static __device__ __forceinline__

DEV u16 f2bf(float f) {
  u32 u = __builtin_bit_cast(u32, f);
  u += 0x7fffu + ((u >> 16) & 1u);
  return (u16)(u >> 16);
}

DEV void gload_lds16(const void* g, void* l) {
  __builtin_amdgcn_global_load_lds(
      (const __attribute__((address_space(1))) u32*)g,
      (__attribute__((address_space(3))) u32*)l, 16, 0, 0);
}

// ---------------- convert kernels ----------------

__global__ __launch_bounds__(256) void cvt_bf16(const float* __restrict__ in,
                                                u16* __restrict__ out, int n4) {
  int i = blockIdx.x * 256 + threadIdx.x;
  const int stride = gridDim.x * 256;
  for (; i < n4; i += stride) {
    const float4 v = ((const float4*)in)[i];
    ushort4 o;
    o.x = f2bf(v.x); o.y = f2bf(v.y); o.z = f2bf(v.z); o.w = f2bf(v.w);
    ((ushort4*)out)[i] = o;
  }
}

// in [K,N] fp32 -> out [N,K] bf16 (transposed)
__global__ __launch_bounds__(256) void cvtT_bf16(const float* __restrict__ in,
                                                 u16* __restrict__ out, int K, int N) {
  int i = blockIdx.x * 256 + threadIdx.x;
  if (i >= N * K) return;
  int n = i / K, k = i - n * K;
  out[i] = f2bf(in[(long)k * N + n]);
}

// ---------------- GEMM: C[M,N] = A[M,K] * BT[N,K]^T ----------------
// 128x128 tile, 4 waves (2x2), 16x16x32 bf16 MFMA, BK=32, global_load_lds x16B.
template <bool OUT_BF16>
__global__ __launch_bounds__(256) void gemm_bt(const u16* __restrict__ A,
                                               const u16* __restrict__ BT,
                                               void* __restrict__ C,
                                               const float* __restrict__ bias,
                                               int M, int N, int K) {
  __shared__ u16 As[128 * 32];
  __shared__ u16 Bs[128 * 32];
  const int t = threadIdx.x;
  const int ntn = N >> 7;
  const int bm = blockIdx.x / ntn, bn = blockIdx.x % ntn;
  const long a0 = (long)bm * 128 * K;
  const long b0 = (long)bn * 128 * K;
  const int w = t >> 6, l = t & 63, lr = l & 15, lhi = l >> 4;
  const int wr = w >> 1, wc = w & 1;
  const int srow = t >> 2, scol = (t & 3) << 3;  // staging: row 0..63, col8

  f32x4 acc[4][4];
#pragma unroll
  for (int i = 0; i < 4; ++i)
#pragma unroll
    for (int j = 0; j < 4; ++j) acc[i][j] = (f32x4){0.f, 0.f, 0.f, 0.f};

  const int kiters = K >> 5;
  for (int kt = 0; kt < kiters; ++kt) {
    const int kof = kt * 32 + scol;
    const u16* ga0 = A + a0 + (long)srow * K + kof;
    const u16* gb0 = BT + b0 + (long)srow * K + kof;
    // wave-uniform LDS bases; HW scatters lane*16B
    gload_lds16(ga0, As + w * 512);
    gload_lds16(ga0 + (long)64 * K, As + 2048 + w * 512);
    gload_lds16(gb0, Bs + w * 512);
    gload_lds16(gb0 + (long)64 * K, Bs + 2048 + w * 512);
    asm volatile("s_waitcnt vmcnt(0)" ::: "memory");
    __syncthreads();

    bf16x8 afr[4], bfr[4];
#pragma unroll
    for (int i = 0; i < 4; ++i)
      afr[i] = *(const bf16x8*)&As[(64 * wr + 16 * i + lr) * 32 + lhi * 8];
#pragma unroll
    for (int j = 0; j < 4; ++j)
      bfr[j] = *(const bf16x8*)&Bs[(64 * wc + 16 * j + lr) * 32 + lhi * 8];
#pragma unroll
    for (int i = 0; i < 4; ++i)
#pragma unroll
      for (int j = 0; j < 4; ++j)
        acc[i][j] = __builtin_amdgcn_mfma_f32_16x16x32_bf16(afr[i], bfr[j], acc[i][j], 0, 0, 0);
    __syncthreads();
  }

  const int row0 = bm * 128 + 64 * wr + 4 * lhi;
  const int col0 = bn * 128 + 64 * wc + lr;
#pragma unroll
  for (int i = 0; i < 4; ++i)
#pragma unroll
    for (int r = 0; r < 4; ++r) {
      const long row = row0 + 16 * i + r;
#pragma unroll
      for (int j = 0; j < 4; ++j) {
        const int col = col0 + 16 * j;
        if (OUT_BF16) {
          ((u16*)C)[row * N + col] = f2bf(acc[i][j][r]);
        } else {
          ((float*)C)[row * N + col] = acc[i][j][r] + bias[col];
        }
      }
    }
}

// ---------------- fused attention ----------------
// one block (256 thr, 4 waves) per (b,h). N=49 padded to 64, hd=64.
__global__ __launch_bounds__(256) void attn_kernel(
    const u16* __restrict__ qkv,        // [B*49, 2304] bf16
    const float* __restrict__ prev,     // [B,12,49,49]
    const float* __restrict__ bias_table,  // [169,12]
    const int* __restrict__ rel_idx,    // [49,49]
    float* __restrict__ prev_out,       // [B,12,49,49]
    u16* __restrict__ attn_out) {       // [B*49, 768] bf16
  __shared__ u16 Qs[64][72];
  __shared__ u16 Ks[64][72];
  __shared__ u16 VTs[64][72];
  __shared__ u16 Ps[64][72];

  const int bh = blockIdx.x;
  const int b = bh / 12, h = bh % 12;
  const int t = threadIdx.x, w = t >> 6, l = t & 63, lr = l & 15, lhi = l >> 4;

  // zero VT (pad cols must be 0 so P*V pad contributes nothing)
  for (int i = t; i < 64 * 72 / 4; i += 256)
    ((unsigned long long*)&VTs[0][0])[i] = 0ull;
  __syncthreads();

  // stage Q,K rows and V transposed
  const u16* base = qkv + (long)(b * 49) * 2304 + h * 64;
  for (int idx = t; idx < 49 * 16; idx += 256) {
    const int n = idx >> 4, c4 = (idx & 15) << 2;
    const u16* rp = base + (long)n * 2304;
    ushort4 qv = *(const ushort4*)(rp + c4);
    ushort4 kv = *(const ushort4*)(rp + 768 + c4);
    ushort4 vv = *(const ushort4*)(rp + 1536 + c4);
    *(ushort4*)&Qs[n][c4] = qv;
    *(ushort4*)&Ks[n][c4] = kv;
    VTs[c4 + 0][n] = vv.x;
    VTs[c4 + 1][n] = vv.y;
    VTs[c4 + 2][n] = vv.z;
    VTs[c4 + 3][n] = vv.w;
  }
  __syncthreads();

  // S = Q K^T : wave w owns rows [16w,16w+16)
  bf16x8 af0 = *(const bf16x8*)&Qs[16 * w + lr][lhi * 8];
  bf16x8 af1 = *(const bf16x8*)&Qs[16 * w + lr][32 + lhi * 8];
  f32x4 sacc[4];
#pragma unroll
  for (int tc = 0; tc < 4; ++tc) {
    sacc[tc] = (f32x4){0.f, 0.f, 0.f, 0.f};
    bf16x8 b0 = *(const bf16x8*)&Ks[16 * tc + lr][lhi * 8];
    bf16x8 b1 = *(const bf16x8*)&Ks[16 * tc + lr][32 + lhi * 8];
    sacc[tc] = __builtin_amdgcn_mfma_f32_16x16x32_bf16(af0, b0, sacc[tc], 0, 0, 0);
    sacc[tc] = __builtin_amdgcn_mfma_f32_16x16x32_bf16(af1, b1, sacc[tc], 0, 0, 0);
  }

  // epilogue + softmax (rows n = 16w + 4*lhi + r, cols m = 16tc + lr)
  const int nrow0 = 16 * w + 4 * lhi;
  const float* prevb = prev + (long)bh * 2401;
  float* pout = prev_out + (long)bh * 2401;
  float rs[4];
#pragma unroll
  for (int r = 0; r < 4; ++r) {
    const int row = nrow0 + r;
    float sv[4];
#pragma unroll
    for (int tc = 0; tc < 4; ++tc) {
      const int col = 16 * tc + lr;
      float s = -INFINITY;
      if (row < 49 && col < 49) {
        s = sacc[tc][r] * 0.125f;
        s += bias_table[rel_idx[row * 49 + col] * 12 + h];
        s += prevb[row * 49 + col];
        pout[row * 49 + col] = s;
      }
      sv[tc] = s;
    }
    float mx = fmaxf(fmaxf(sv[0], sv[1]), fmaxf(sv[2], sv[3]));
#pragma unroll
    for (int off = 8; off; off >>= 1) mx = fmaxf(mx, __shfl_xor(mx, off, 16));
    float e[4], sum = 0.f;
#pragma unroll
    for (int tc = 0; tc < 4; ++tc) {
      e[tc] = __expf(sv[tc] - mx);
      sum += e[tc];
    }
#pragma unroll
    for (int off = 8; off; off >>= 1) sum += __shfl_xor(sum, off, 16);
    rs[r] = 1.0f / sum;
#pragma unroll
    for (int tc = 0; tc < 4; ++tc) Ps[row][16 * tc + lr] = f2bf(e[tc]);
  }
  __syncthreads();

  // O = P V : wave w owns rows [16w,16w+16), cols d in 4 tiles
  bf16x8 pf0 = *(const bf16x8*)&Ps[16 * w + lr][lhi * 8];
  bf16x8 pf1 = *(const bf16x8*)&Ps[16 * w + lr][32 + lhi * 8];
  f32x4 oacc[4];
#pragma unroll
  for (int dc = 0; dc < 4; ++dc) {
    oacc[dc] = (f32x4){0.f, 0.f, 0.f, 0.f};
    bf16x8 v0 = *(const bf16x8*)&VTs[16 * dc + lr][lhi * 8];
    bf16x8 v1 = *(const bf16x8*)&VTs[16 * dc + lr][32 + lhi * 8];
    oacc[dc] = __builtin_amdgcn_mfma_f32_16x16x32_bf16(pf0, v0, oacc[dc], 0, 0, 0);
    oacc[dc] = __builtin_amdgcn_mfma_f32_16x16x32_bf16(pf1, v1, oacc[dc], 0, 0, 0);
  }
  u16* ob = attn_out + (long)(b * 49) * 768 + h * 64;
#pragma unroll
  for (int r = 0; r < 4; ++r) {
    const int row = nrow0 + r;
    if (row < 49) {
#pragma unroll
      for (int dc = 0; dc < 4; ++dc)
        ob[(long)row * 768 + 16 * dc + lr] = f2bf(oacc[dc][r] * rs[r]);
    }
  }
}

// ---------------- launch ----------------
extern "C" void kernel_launch(void* const* d_in, const int* in_sizes, int n_in,
                              void* d_out, int out_size, void* d_ws, size_t ws_size,
                              hipStream_t stream) {
  const float* x = (const float*)d_in[0];
  const float* prev = (const float*)d_in[1];
  const float* qkv_w = (const float*)d_in[2];
  const float* proj_w = (const float*)d_in[3];
  const float* proj_b = (const float*)d_in[4];
  const float* bias_table = (const float*)d_in[5];
  const int* rel_idx = (const int*)d_in[6];

  const int B = in_sizes[0] / (49 * 768);  // 1024
  const int M = B * 49;                    // 50176 = 392*128

  float* out0 = (float*)d_out;                    // [M,768]
  float* out1 = out0 + (size_t)M * 768;           // [B,12,49,49]

  // workspace layout (needs ~313 MB)
  char* ws = (char*)d_ws;
  u16* xbf = (u16*)ws;                                     // M*768 bf16 (later reused for attn_out)
  u16* qkvbf = (u16*)(ws + (size_t)M * 768 * 2);           // M*2304 bf16
  u16* qkvwT = (u16*)(ws + (size_t)M * 768 * 2 + (size_t)M * 2304 * 2);  // [2304,768]
  u16* projwT = qkvwT + 2304 * 768;                        // [768,768]

  cvt_bf16<<<2048, 256, 0, stream>>>(x, xbf, M * 768 / 4);
  cvtT_bf16<<<(2304 * 768 + 255) / 256, 256, 0, stream>>>(qkv_w, qkvwT, 768, 2304);
  cvtT_bf16<<<(768 * 768 + 255) / 256, 256, 0, stream>>>(proj_w, projwT, 768, 768);

  gemm_bt<true><<<(M / 128) * (2304 / 128), 256, 0, stream>>>(
      xbf, qkvwT, qkvbf, nullptr, M, 2304, 768);

  attn_kernel<<<B * 12, 256, 0, stream>>>(qkvbf, prev, bias_table, rel_idx, out1, xbf);

  gemm_bt<false><<<(M / 128) * (768 / 128), 256, 0, stream>>>(
      xbf, projwT, out0, proj_b, M, 768, 768);
}

// Round 2
// 593.921 us; speedup vs baseline: 1.0970x; 1.0970x over previous
//
#include <hip/hip_runtime.h>

typedef unsigned short u16;
typedef unsigned int u32;
typedef float f32x4 __attribute__((ext_vector_type(4)));
typedef __bf16 bf16x8 __attribute__((ext_vector_type(8)));

#define DEV static __device__ __forceinline__

DEV u16 f2bf(float f) {
  u32 u = __builtin_bit_cast(u32, f);
  u += 0x7fffu + ((u >> 16) & 1u);
  return (u16)(u >> 16);
}

DEV void gload_lds16(const void* g, void* l) {
  __builtin_amdgcn_global_load_lds(
      (const __attribute__((address_space(1))) u32*)g,
      (__attribute__((address_space(3))) u32*)l, 16, 0, 0);
}

// ---------------- convert kernels ----------------

__global__ __launch_bounds__(256) void cvt_bf16(const float* __restrict__ in,
                                                u16* __restrict__ out, int n4) {
  int i = blockIdx.x * 256 + threadIdx.x;
  const int stride = gridDim.x * 256;
  for (; i < n4; i += stride) {
    const float4 v = ((const float4*)in)[i];
    ushort4 o;
    o.x = f2bf(v.x); o.y = f2bf(v.y); o.z = f2bf(v.z); o.w = f2bf(v.w);
    ((ushort4*)out)[i] = o;
  }
}

// in [K,N] fp32 -> out [N,K] bf16 (transposed)
__global__ __launch_bounds__(256) void cvtT_bf16(const float* __restrict__ in,
                                                 u16* __restrict__ out, int K, int N) {
  int i = blockIdx.x * 256 + threadIdx.x;
  if (i >= N * K) return;
  int n = i / K, k = i - n * K;
  out[i] = f2bf(in[(long)k * N + n]);
}

// ---------------- 256x256 deep-pipelined GEMM ----------------
// C[M,N] = A[M,K] * BT[N,K]^T.  512 thr = 8 waves (2x4), per-wave 128x64 out.
// BK=32, 4 LDS buffers (128 KiB), stage t+3 while computing t, vmcnt(8),
// one raw s_barrier per K-tile, XOR-swizzled LDS (both sides), XCD swizzle.
template <bool OUT_BF16>
__global__ __launch_bounds__(512, 2) void gemm256(
    const u16* __restrict__ A, const u16* __restrict__ BT,
    void* __restrict__ C, const float* __restrict__ bias,
    int M, int N, int K, int nbn) {
  __shared__ alignas(16) char lds[131072];
  const int t = threadIdx.x;
  const int w = t >> 6, l = t & 63, lr = l & 15, lhi = l >> 4;
  const int wr = w >> 2, wc = w & 3;

  // bijective XCD-chunked swizzle (m204)
  const int nwg = gridDim.x;
  const int q = nwg >> 3, r = nwg & 7;
  const int xcd = blockIdx.x & 7, lid = blockIdx.x >> 3;
  const int swz = (xcd < r ? xcd * (q + 1) : r * (q + 1) + (xcd - r) * q) + lid;
  const int bm = swz / nbn, bn = swz % nbn;

  const int T = K >> 5;
  const long Kb = (long)K * 2;

  // staging: LDS is written LINEARLY by global_load_lds; source is
  // inverse-swizzled so that read-side addr^((row&3)<<4) finds the data.
  const int srow = w * 16 + (l >> 2);
  const int scolb = ((l & 3) ^ ((l >> 2) & 3)) << 4;
  const char* gA0 = (const char*)A + (long)(bm * 256 + srow) * Kb + scolb;
  const char* gA1 = gA0 + 128 * Kb;
  const char* gB0 = (const char*)BT + (long)(bn * 256 + srow) * Kb + scolb;
  const char* gB1 = gB0 + 128 * Kb;
  const int ldA0 = w * 1024, ldA1 = 8192 + w * 1024;
  const int ldB0 = 16384 + w * 1024, ldB1 = 24576 + w * 1024;

#define STAGE(tt)                               \
  {                                             \
    const int bb = ((tt) & 3) * 32768;          \
    const long ko = (long)(tt) * 64;            \
    gload_lds16(gA0 + ko, lds + bb + ldA0);     \
    gload_lds16(gA1 + ko, lds + bb + ldA1);     \
    gload_lds16(gB0 + ko, lds + bb + ldB0);     \
    gload_lds16(gB1 + ko, lds + bb + ldB1);     \
  }

  int aoff[8], boff[4];
#pragma unroll
  for (int m = 0; m < 8; ++m)
    aoff[m] = (wr * 128 + m * 16 + lr) * 64 + ((lhi ^ (lr & 3)) << 4);
#pragma unroll
  for (int n = 0; n < 4; ++n)
    boff[n] = 16384 + (wc * 64 + n * 16 + lr) * 64 + ((lhi ^ (lr & 3)) << 4);

  f32x4 acc[8][4];
#pragma unroll
  for (int m = 0; m < 8; ++m)
#pragma unroll
    for (int n = 0; n < 4; ++n) acc[m][n] = (f32x4){0.f, 0.f, 0.f, 0.f};
  bf16x8 afr[8], bfr[4];

  // prologue: stage tiles 0,1,2; wait tile 0 landed (2 tiles stay in flight)
  STAGE(0); STAGE(1); STAGE(2);
  asm volatile("s_waitcnt vmcnt(8)" ::: "memory");
  __builtin_amdgcn_s_barrier();
  asm volatile("" ::: "memory");
#pragma unroll
  for (int n = 0; n < 4; ++n) bfr[n] = *(const bf16x8*)(lds + boff[n]);
#pragma unroll
  for (int m = 0; m < 4; ++m) afr[m] = *(const bf16x8*)(lds + aoff[m]);

  for (int kt = 0; kt < T; ++kt) {
    if (kt + 3 < T) STAGE(kt + 3);
    {
      const int bb = (kt & 3) * 32768;
#pragma unroll
      for (int m = 4; m < 8; ++m) afr[m] = *(const bf16x8*)(lds + bb + aoff[m]);
    }
    __builtin_amdgcn_s_setprio(1);
#pragma unroll
    for (int m = 0; m < 4; ++m)
#pragma unroll
      for (int n = 0; n < 4; ++n)
        acc[m][n] = __builtin_amdgcn_mfma_f32_16x16x32_bf16(afr[m], bfr[n], acc[m][n], 0, 0, 0);
    __builtin_amdgcn_s_setprio(0);
    __builtin_amdgcn_s_setprio(1);
#pragma unroll
    for (int m = 4; m < 8; ++m)
#pragma unroll
      for (int n = 0; n < 4; ++n)
        acc[m][n] = __builtin_amdgcn_mfma_f32_16x16x32_bf16(afr[m], bfr[n], acc[m][n], 0, 0, 0);
    __builtin_amdgcn_s_setprio(0);
    // tile kt fully consumed; allow next iter to overwrite buf[kt&3].
    // vmcnt(8): tiles kt+2,kt+3 may be in flight; kt+1 is landed.
    asm volatile("s_waitcnt vmcnt(8)" ::: "memory");
    __builtin_amdgcn_s_barrier();
    asm volatile("" ::: "memory");
    if (kt + 1 < T) {
      const int bb = ((kt + 1) & 3) * 32768;
#pragma unroll
      for (int n = 0; n < 4; ++n) bfr[n] = *(const bf16x8*)(lds + bb + boff[n]);
#pragma unroll
      for (int m = 0; m < 4; ++m) afr[m] = *(const bf16x8*)(lds + bb + aoff[m]);
    }
  }
#undef STAGE

  const int row0 = bm * 256 + wr * 128 + 4 * lhi;
  const int col0 = bn * 256 + wc * 64 + lr;
  if (OUT_BF16) {
    u16* Cc = (u16*)C;
#pragma unroll
    for (int m = 0; m < 8; ++m)
#pragma unroll
      for (int rr = 0; rr < 4; ++rr) {
        const long row = row0 + m * 16 + rr;
#pragma unroll
        for (int n = 0; n < 4; ++n)
          Cc[row * N + col0 + n * 16] = f2bf(acc[m][n][rr]);
      }
  } else {
    float* Cf = (float*)C;
    float bv[4];
#pragma unroll
    for (int n = 0; n < 4; ++n) bv[n] = bias[col0 + n * 16];
#pragma unroll
    for (int m = 0; m < 8; ++m)
#pragma unroll
      for (int rr = 0; rr < 4; ++rr) {
        const long row = row0 + m * 16 + rr;
#pragma unroll
        for (int n = 0; n < 4; ++n)
          Cf[row * N + col0 + n * 16] = acc[m][n][rr] + bv[n];
      }
  }
}

// ---------------- fused attention ----------------
// one block (256 thr, 4 waves) per (b,h). N=49 padded to 64, hd=64.
__global__ __launch_bounds__(256) void attn_kernel(
    const u16* __restrict__ qkv,        // [B*49, 2304] bf16
    const float* __restrict__ prev,     // [B,12,49,49]
    const float* __restrict__ bias_table,  // [169,12]
    const int* __restrict__ rel_idx,    // [49,49]
    float* __restrict__ prev_out,       // [B,12,49,49]
    u16* __restrict__ attn_out) {       // [B*49, 768] bf16
  __shared__ u16 Qs[64][72];
  __shared__ u16 Ks[64][72];
  __shared__ u16 VTs[64][72];
  __shared__ u16 Ps[64][72];

  const int bh = blockIdx.x;
  const int b = bh / 12, h = bh % 12;
  const int t = threadIdx.x, w = t >> 6, l = t & 63, lr = l & 15, lhi = l >> 4;

  for (int i = t; i < 64 * 72 / 4; i += 256)
    ((unsigned long long*)&VTs[0][0])[i] = 0ull;
  __syncthreads();

  const u16* base = qkv + (long)(b * 49) * 2304 + h * 64;
  for (int idx = t; idx < 49 * 16; idx += 256) {
    const int n = idx >> 4, c4 = (idx & 15) << 2;
    const u16* rp = base + (long)n * 2304;
    ushort4 qv = *(const ushort4*)(rp + c4);
    ushort4 kv = *(const ushort4*)(rp + 768 + c4);
    ushort4 vv = *(const ushort4*)(rp + 1536 + c4);
    *(ushort4*)&Qs[n][c4] = qv;
    *(ushort4*)&Ks[n][c4] = kv;
    VTs[c4 + 0][n] = vv.x;
    VTs[c4 + 1][n] = vv.y;
    VTs[c4 + 2][n] = vv.z;
    VTs[c4 + 3][n] = vv.w;
  }
  __syncthreads();

  bf16x8 af0 = *(const bf16x8*)&Qs[16 * w + lr][lhi * 8];
  bf16x8 af1 = *(const bf16x8*)&Qs[16 * w + lr][32 + lhi * 8];
  f32x4 sacc[4];
#pragma unroll
  for (int tc = 0; tc < 4; ++tc) {
    sacc[tc] = (f32x4){0.f, 0.f, 0.f, 0.f};
    bf16x8 b0 = *(const bf16x8*)&Ks[16 * tc + lr][lhi * 8];
    bf16x8 b1 = *(const bf16x8*)&Ks[16 * tc + lr][32 + lhi * 8];
    sacc[tc] = __builtin_amdgcn_mfma_f32_16x16x32_bf16(af0, b0, sacc[tc], 0, 0, 0);
    sacc[tc] = __builtin_amdgcn_mfma_f32_16x16x32_bf16(af1, b1, sacc[tc], 0, 0, 0);
  }

  const int nrow0 = 16 * w + 4 * lhi;
  const float* prevb = prev + (long)bh * 2401;
  float* pout = prev_out + (long)bh * 2401;
  float rs[4];
#pragma unroll
  for (int r = 0; r < 4; ++r) {
    const int row = nrow0 + r;
    float sv[4];
#pragma unroll
    for (int tc = 0; tc < 4; ++tc) {
      const int col = 16 * tc + lr;
      float s = -INFINITY;
      if (row < 49 && col < 49) {
        s = sacc[tc][r] * 0.125f;
        s += bias_table[rel_idx[row * 49 + col] * 12 + h];
        s += prevb[row * 49 + col];
        pout[row * 49 + col] = s;
      }
      sv[tc] = s;
    }
    float mx = fmaxf(fmaxf(sv[0], sv[1]), fmaxf(sv[2], sv[3]));
#pragma unroll
    for (int off = 8; off; off >>= 1) mx = fmaxf(mx, __shfl_xor(mx, off, 16));
    float e[4], sum = 0.f;
#pragma unroll
    for (int tc = 0; tc < 4; ++tc) {
      e[tc] = __expf(sv[tc] - mx);
      sum += e[tc];
    }
#pragma unroll
    for (int off = 8; off; off >>= 1) sum += __shfl_xor(sum, off, 16);
    rs[r] = 1.0f / sum;
#pragma unroll
    for (int tc = 0; tc < 4; ++tc) Ps[row][16 * tc + lr] = f2bf(e[tc]);
  }
  __syncthreads();

  bf16x8 pf0 = *(const bf16x8*)&Ps[16 * w + lr][lhi * 8];
  bf16x8 pf1 = *(const bf16x8*)&Ps[16 * w + lr][32 + lhi * 8];
  f32x4 oacc[4];
#pragma unroll
  for (int dc = 0; dc < 4; ++dc) {
    oacc[dc] = (f32x4){0.f, 0.f, 0.f, 0.f};
    bf16x8 v0 = *(const bf16x8*)&VTs[16 * dc + lr][lhi * 8];
    bf16x8 v1 = *(const bf16x8*)&VTs[16 * dc + lr][32 + lhi * 8];
    oacc[dc] = __builtin_amdgcn_mfma_f32_16x16x32_bf16(pf0, v0, oacc[dc], 0, 0, 0);
    oacc[dc] = __builtin_amdgcn_mfma_f32_16x16x32_bf16(pf1, v1, oacc[dc], 0, 0, 0);
  }
  u16* ob = attn_out + (long)(b * 49) * 768 + h * 64;
#pragma unroll
  for (int r = 0; r < 4; ++r) {
    const int row = nrow0 + r;
    if (row < 49) {
#pragma unroll
      for (int dc = 0; dc < 4; ++dc)
        ob[(long)row * 768 + 16 * dc + lr] = f2bf(oacc[dc][r] * rs[r]);
    }
  }
}

// ---------------- launch ----------------
extern "C" void kernel_launch(void* const* d_in, const int* in_sizes, int n_in,
                              void* d_out, int out_size, void* d_ws, size_t ws_size,
                              hipStream_t stream) {
  const float* x = (const float*)d_in[0];
  const float* prev = (const float*)d_in[1];
  const float* qkv_w = (const float*)d_in[2];
  const float* proj_w = (const float*)d_in[3];
  const float* proj_b = (const float*)d_in[4];
  const float* bias_table = (const float*)d_in[5];
  const int* rel_idx = (const int*)d_in[6];

  const int B = in_sizes[0] / (49 * 768);  // 1024
  const int M = B * 49;                    // 50176 = 196*256

  float* out0 = (float*)d_out;             // [M,768]
  float* out1 = out0 + (size_t)M * 768;    // [B,12,49,49]

  char* ws = (char*)d_ws;
  u16* xbf = (u16*)ws;                                     // M*768 bf16 (reused as attn_out)
  u16* qkvbf = (u16*)(ws + (size_t)M * 768 * 2);           // M*2304 bf16
  u16* qkvwT = (u16*)(ws + (size_t)M * 768 * 2 + (size_t)M * 2304 * 2);  // [2304,768]
  u16* projwT = qkvwT + 2304 * 768;                        // [768,768]

  cvt_bf16<<<2048, 256, 0, stream>>>(x, xbf, M * 768 / 4);
  cvtT_bf16<<<(2304 * 768 + 255) / 256, 256, 0, stream>>>(qkv_w, qkvwT, 768, 2304);
  cvtT_bf16<<<(768 * 768 + 255) / 256, 256, 0, stream>>>(proj_w, projwT, 768, 768);

  gemm256<true><<<(M / 256) * (2304 / 256), 512, 0, stream>>>(
      xbf, qkvwT, qkvbf, nullptr, M, 2304, 768, 2304 / 256);

  attn_kernel<<<B * 12, 256, 0, stream>>>(qkvbf, prev, bias_table, rel_idx, out1, xbf);

  gemm256<false><<<(M / 256) * (768 / 256), 512, 0, stream>>>(
      xbf, projwT, out0, proj_b, M, 768, 768, 768 / 256);
}

// Round 3
// 542.821 us; speedup vs baseline: 1.2003x; 1.0941x over previous
//
#include <hip/hip_runtime.h>

typedef unsigned short u16;
typedef unsigned int u32;
typedef float f32x4 __attribute__((ext_vector_type(4)));
typedef __bf16 bf16x8 __attribute__((ext_vector_type(8)));

#define DEV static __device__ __forceinline__

DEV u16 f2bf(float f) {
  u32 u = __builtin_bit_cast(u32, f);
  u += 0x7fffu + ((u >> 16) & 1u);
  return (u16)(u >> 16);
}

DEV void gload_lds16(const void* g, void* l) {
  __builtin_amdgcn_global_load_lds(
      (const __attribute__((address_space(1))) u32*)g,
      (__attribute__((address_space(3))) u32*)l, 16, 0, 0);
}

// ---------------- convert kernels ----------------

__global__ __launch_bounds__(256) void cvt_bf16(const float* __restrict__ in,
                                                u16* __restrict__ out, int n4) {
  int i = blockIdx.x * 256 + threadIdx.x;
  const int stride = gridDim.x * 256;
  for (; i < n4; i += stride) {
    const float4 v = ((const float4*)in)[i];
    ushort4 o;
    o.x = f2bf(v.x); o.y = f2bf(v.y); o.z = f2bf(v.z); o.w = f2bf(v.w);
    ((ushort4*)out)[i] = o;
  }
}

// in [K,N] fp32 -> out [N,K] bf16 (transposed)
__global__ __launch_bounds__(256) void cvtT_bf16(const float* __restrict__ in,
                                                 u16* __restrict__ out, int K, int N) {
  int i = blockIdx.x * 256 + threadIdx.x;
  if (i >= N * K) return;
  int n = i / K, k = i - n * K;
  out[i] = f2bf(in[(long)k * N + n]);
}

// biasM[h][p] = bias_table[rel_idx[p]*12 + h], p < 2401
__global__ __launch_bounds__(256) void bias_pre(const float* __restrict__ bias_table,
                                                const int* __restrict__ rel_idx,
                                                float* __restrict__ biasM) {
  int i = blockIdx.x * 256 + threadIdx.x;
  if (i >= 12 * 2401) return;
  int h = i / 2401, p = i - h * 2401;
  biasM[i] = bias_table[rel_idx[p] * 12 + h];
}

// ---------------- 256x256 deep-pipelined GEMM ----------------
template <bool OUT_BF16>
__global__ __launch_bounds__(512, 2) void gemm256(
    const u16* __restrict__ A, const u16* __restrict__ BT,
    void* __restrict__ C, const float* __restrict__ bias,
    int M, int N, int K, int nbn) {
  __shared__ alignas(16) char lds[131072];
  const int t = threadIdx.x;
  const int w = t >> 6, l = t & 63, lr = l & 15, lhi = l >> 4;
  const int wr = w >> 2, wc = w & 3;

  const int nwg = gridDim.x;
  const int q = nwg >> 3, r = nwg & 7;
  const int xcd = blockIdx.x & 7, lid = blockIdx.x >> 3;
  const int swz = (xcd < r ? xcd * (q + 1) : r * (q + 1) + (xcd - r) * q) + lid;
  const int bm = swz / nbn, bn = swz % nbn;

  const int T = K >> 5;
  const long Kb = (long)K * 2;

  const int srow = w * 16 + (l >> 2);
  const int scolb = ((l & 3) ^ ((l >> 2) & 3)) << 4;
  const char* gA0 = (const char*)A + (long)(bm * 256 + srow) * Kb + scolb;
  const char* gA1 = gA0 + 128 * Kb;
  const char* gB0 = (const char*)BT + (long)(bn * 256 + srow) * Kb + scolb;
  const char* gB1 = gB0 + 128 * Kb;
  const int ldA0 = w * 1024, ldA1 = 8192 + w * 1024;
  const int ldB0 = 16384 + w * 1024, ldB1 = 24576 + w * 1024;

#define STAGE(tt)                               \
  {                                             \
    const int bb = ((tt) & 3) * 32768;          \
    const long ko = (long)(tt) * 64;            \
    gload_lds16(gA0 + ko, lds + bb + ldA0);     \
    gload_lds16(gA1 + ko, lds + bb + ldA1);     \
    gload_lds16(gB0 + ko, lds + bb + ldB0);     \
    gload_lds16(gB1 + ko, lds + bb + ldB1);     \
  }

  int aoff[8], boff[4];
#pragma unroll
  for (int m = 0; m < 8; ++m)
    aoff[m] = (wr * 128 + m * 16 + lr) * 64 + ((lhi ^ (lr & 3)) << 4);
#pragma unroll
  for (int n = 0; n < 4; ++n)
    boff[n] = 16384 + (wc * 64 + n * 16 + lr) * 64 + ((lhi ^ (lr & 3)) << 4);

  f32x4 acc[8][4];
#pragma unroll
  for (int m = 0; m < 8; ++m)
#pragma unroll
    for (int n = 0; n < 4; ++n) acc[m][n] = (f32x4){0.f, 0.f, 0.f, 0.f};
  bf16x8 afr[8], bfr[4];

  STAGE(0); STAGE(1); STAGE(2);
  asm volatile("s_waitcnt vmcnt(8)" ::: "memory");
  __builtin_amdgcn_s_barrier();
  asm volatile("" ::: "memory");
#pragma unroll
  for (int n = 0; n < 4; ++n) bfr[n] = *(const bf16x8*)(lds + boff[n]);
#pragma unroll
  for (int m = 0; m < 4; ++m) afr[m] = *(const bf16x8*)(lds + aoff[m]);

  for (int kt = 0; kt < T; ++kt) {
    if (kt + 3 < T) STAGE(kt + 3);
    {
      const int bb = (kt & 3) * 32768;
#pragma unroll
      for (int m = 4; m < 8; ++m) afr[m] = *(const bf16x8*)(lds + bb + aoff[m]);
    }
    __builtin_amdgcn_s_setprio(1);
#pragma unroll
    for (int m = 0; m < 4; ++m)
#pragma unroll
      for (int n = 0; n < 4; ++n)
        acc[m][n] = __builtin_amdgcn_mfma_f32_16x16x32_bf16(afr[m], bfr[n], acc[m][n], 0, 0, 0);
    __builtin_amdgcn_s_setprio(0);
    __builtin_amdgcn_s_setprio(1);
#pragma unroll
    for (int m = 4; m < 8; ++m)
#pragma unroll
      for (int n = 0; n < 4; ++n)
        acc[m][n] = __builtin_amdgcn_mfma_f32_16x16x32_bf16(afr[m], bfr[n], acc[m][n], 0, 0, 0);
    __builtin_amdgcn_s_setprio(0);
    asm volatile("s_waitcnt vmcnt(8)" ::: "memory");
    __builtin_amdgcn_s_barrier();
    asm volatile("" ::: "memory");
    if (kt + 1 < T) {
      const int bb = ((kt + 1) & 3) * 32768;
#pragma unroll
      for (int n = 0; n < 4; ++n) bfr[n] = *(const bf16x8*)(lds + bb + boff[n]);
#pragma unroll
      for (int m = 0; m < 4; ++m) afr[m] = *(const bf16x8*)(lds + bb + aoff[m]);
    }
  }
#undef STAGE

  const int row0 = bm * 256 + wr * 128 + 4 * lhi;
  const int col0 = bn * 256 + wc * 64 + lr;
  if (OUT_BF16) {
    u16* Cc = (u16*)C;
#pragma unroll
    for (int m = 0; m < 8; ++m)
#pragma unroll
      for (int rr = 0; rr < 4; ++rr) {
        const long row = row0 + m * 16 + rr;
#pragma unroll
        for (int n = 0; n < 4; ++n)
          Cc[row * N + col0 + n * 16] = f2bf(acc[m][n][rr]);
      }
  } else {
    float* Cf = (float*)C;
    float bv[4];
#pragma unroll
    for (int n = 0; n < 4; ++n) bv[n] = bias[col0 + n * 16];
#pragma unroll
    for (int m = 0; m < 8; ++m)
#pragma unroll
      for (int rr = 0; rr < 4; ++rr) {
        const long row = row0 + m * 16 + rr;
#pragma unroll
        for (int n = 0; n < 4; ++n)
          Cf[row * N + col0 + n * 16] = acc[m][n][rr] + bv[n];
      }
  }
}

// ---------------- fused attention ----------------
// one block (256 thr, 4 waves) per (b,h). N=49 padded to 64, hd=64.
// prev+bias staged to LDS coalesced; scores written back to LDS then
// streamed out; Ps aliases Qs; 2 barriers total.
__global__ __launch_bounds__(256) void attn_kernel(
    const u16* __restrict__ qkv,        // [B*49, 2304] bf16
    const float* __restrict__ prev,     // [B,12,49,49]
    const float* __restrict__ biasM,    // [12,49*49]
    float* __restrict__ prev_out,       // [B,12,49,49]
    u16* __restrict__ attn_out) {       // [B*49, 768] bf16
  __shared__ u16 Qs[64][72];   // aliased as Ps after QK^T
  __shared__ u16 Ks[64][72];
  __shared__ u16 VTs[64][72];
  __shared__ float SB[2432];   // prev+bias, then scores

  const int bh = blockIdx.x;
  const int b = bh / 12, h = bh % 12;
  const int t = threadIdx.x, w = t >> 6, l = t & 63, lr = l & 15, lhi = l >> 4;

  // ---- phase 1: stage everything (one big MLP burst) ----
  const u16* base = qkv + (long)(b * 49) * 2304 + h * 64;
  for (int idx = t; idx < 49 * 16; idx += 256) {
    const int n = idx >> 4, c4 = (idx & 15) << 2;
    const u16* rp = base + (long)n * 2304;
    ushort4 qv = *(const ushort4*)(rp + c4);
    ushort4 kv = *(const ushort4*)(rp + 768 + c4);
    ushort4 vv = *(const ushort4*)(rp + 1536 + c4);
    *(ushort4*)&Qs[n][c4] = qv;
    *(ushort4*)&Ks[n][c4] = kv;
    VTs[c4 + 0][n] = vv.x;
    VTs[c4 + 1][n] = vv.y;
    VTs[c4 + 2][n] = vv.z;
    VTs[c4 + 3][n] = vv.w;
  }
  // zero V^T pad cols n=49..63
  for (int idx = t; idx < 1024; idx += 256) {
    const int j = idx & 15;
    if (j) VTs[idx >> 4][48 + j] = 0;
  }
  // prev + bias -> LDS (coalesced scalar dwords; base only 4B-aligned)
  {
    const float* pv = prev + (long)bh * 2401;
    const float* bm = biasM + h * 2401;
    for (int i = t; i < 2401; i += 256) SB[i] = pv[i] + bm[i];
  }
  __syncthreads();

  // ---- QK^T ----
  bf16x8 af0 = *(const bf16x8*)&Qs[16 * w + lr][lhi * 8];
  bf16x8 af1 = *(const bf16x8*)&Qs[16 * w + lr][32 + lhi * 8];
  f32x4 sacc[4];
#pragma unroll
  for (int tc = 0; tc < 4; ++tc) {
    sacc[tc] = (f32x4){0.f, 0.f, 0.f, 0.f};
    bf16x8 b0 = *(const bf16x8*)&Ks[16 * tc + lr][lhi * 8];
    bf16x8 b1 = *(const bf16x8*)&Ks[16 * tc + lr][32 + lhi * 8];
    sacc[tc] = __builtin_amdgcn_mfma_f32_16x16x32_bf16(af0, b0, sacc[tc], 0, 0, 0);
    sacc[tc] = __builtin_amdgcn_mfma_f32_16x16x32_bf16(af1, b1, sacc[tc], 0, 0, 0);
  }

  // ---- epilogue + softmax (LDS-only critical path) ----
  u16 (*Ps)[72] = Qs;  // alias: wave w reads only its own Q rows before writing
  const int nrow0 = 16 * w + 4 * lhi;
  float rs[4];
#pragma unroll
  for (int r = 0; r < 4; ++r) {
    const int row = nrow0 + r;
    const bool rv = row < 49;
    float sv[4];
#pragma unroll
    for (int tc = 0; tc < 4; ++tc) {
      const int col = 16 * tc + lr;
      const bool valid = rv && (col < 49);
      const int sidx = (row < 49 ? row : 48) * 49 + (col < 49 ? col : 48);
      const float pb = SB[sidx];  // clamped, always in-bounds
      const float s = sacc[tc][r] * 0.125f + pb;
      if (valid) SB[sidx] = s;
      sv[tc] = valid ? s : -INFINITY;
    }
    float mx = fmaxf(fmaxf(sv[0], sv[1]), fmaxf(sv[2], sv[3]));
#pragma unroll
    for (int off = 8; off; off >>= 1) mx = fmaxf(mx, __shfl_xor(mx, off, 16));
    float e[4], sum = 0.f;
#pragma unroll
    for (int tc = 0; tc < 4; ++tc) {
      e[tc] = __expf(sv[tc] - mx);
      sum += e[tc];
    }
#pragma unroll
    for (int off = 8; off; off >>= 1) sum += __shfl_xor(sum, off, 16);
    rs[r] = 1.0f / sum;
#pragma unroll
    for (int tc = 0; tc < 4; ++tc)
      Ps[row][16 * tc + lr] = rv ? f2bf(e[tc]) : (u16)0;
  }
  __syncthreads();

  // ---- P*V (Ps rows are wave-local) ----
  bf16x8 pf0 = *(const bf16x8*)&Ps[16 * w + lr][lhi * 8];
  bf16x8 pf1 = *(const bf16x8*)&Ps[16 * w + lr][32 + lhi * 8];
  f32x4 oacc[4];
#pragma unroll
  for (int dc = 0; dc < 4; ++dc) {
    oacc[dc] = (f32x4){0.f, 0.f, 0.f, 0.f};
    bf16x8 v0 = *(const bf16x8*)&VTs[16 * dc + lr][lhi * 8];
    bf16x8 v1 = *(const bf16x8*)&VTs[16 * dc + lr][32 + lhi * 8];
    oacc[dc] = __builtin_amdgcn_mfma_f32_16x16x32_bf16(pf0, v0, oacc[dc], 0, 0, 0);
    oacc[dc] = __builtin_amdgcn_mfma_f32_16x16x32_bf16(pf1, v1, oacc[dc], 0, 0, 0);
  }
  u16* ob = attn_out + (long)(b * 49) * 768 + h * 64;
#pragma unroll
  for (int r = 0; r < 4; ++r) {
    const int row = nrow0 + r;
    if (row < 49) {
#pragma unroll
      for (int dc = 0; dc < 4; ++dc)
        ob[(long)row * 768 + 16 * dc + lr] = f2bf(oacc[dc][r] * rs[r]);
    }
  }

  // ---- stream prev_out coalesced from LDS ----
  {
    float* pout = prev_out + (long)bh * 2401;
    for (int i = t; i < 2401; i += 256) pout[i] = SB[i];
  }
}

// ---------------- launch ----------------
extern "C" void kernel_launch(void* const* d_in, const int* in_sizes, int n_in,
                              void* d_out, int out_size, void* d_ws, size_t ws_size,
                              hipStream_t stream) {
  const float* x = (const float*)d_in[0];
  const float* prev = (const float*)d_in[1];
  const float* qkv_w = (const float*)d_in[2];
  const float* proj_w = (const float*)d_in[3];
  const float* proj_b = (const float*)d_in[4];
  const float* bias_table = (const float*)d_in[5];
  const int* rel_idx = (const int*)d_in[6];

  const int B = in_sizes[0] / (49 * 768);  // 1024
  const int M = B * 49;                    // 50176 = 196*256

  float* out0 = (float*)d_out;             // [M,768]
  float* out1 = out0 + (size_t)M * 768;    // [B,12,49,49]

  char* ws = (char*)d_ws;
  u16* xbf = (u16*)ws;                                     // M*768 bf16 (reused as attn_out)
  u16* qkvbf = (u16*)(ws + (size_t)M * 768 * 2);           // M*2304 bf16
  u16* qkvwT = (u16*)(ws + (size_t)M * 768 * 2 + (size_t)M * 2304 * 2);  // [2304,768]
  u16* projwT = qkvwT + 2304 * 768;                        // [768,768]
  float* biasM = (float*)(projwT + 768 * 768);             // [12,2401]

  bias_pre<<<(12 * 2401 + 255) / 256, 256, 0, stream>>>(bias_table, rel_idx, biasM);
  cvt_bf16<<<2048, 256, 0, stream>>>(x, xbf, M * 768 / 4);
  cvtT_bf16<<<(2304 * 768 + 255) / 256, 256, 0, stream>>>(qkv_w, qkvwT, 768, 2304);
  cvtT_bf16<<<(768 * 768 + 255) / 256, 256, 0, stream>>>(proj_w, projwT, 768, 768);

  gemm256<true><<<(M / 256) * (2304 / 256), 512, 0, stream>>>(
      xbf, qkvwT, qkvbf, nullptr, M, 2304, 768, 2304 / 256);

  attn_kernel<<<B * 12, 256, 0, stream>>>(qkvbf, prev, biasM, out1, xbf);

  gemm256<false><<<(M / 256) * (768 / 256), 512, 0, stream>>>(
      xbf, projwT, out0, proj_b, M, 768, 768, 768 / 256);
}

// Round 5
// 536.122 us; speedup vs baseline: 1.2153x; 1.0125x over previous
//
#include <hip/hip_runtime.h>

typedef unsigned short u16;
typedef unsigned int u32;
typedef float f32x4 __attribute__((ext_vector_type(4)));
typedef __bf16 bf16x8 __attribute__((ext_vector_type(8)));

#define DEV static __device__ __forceinline__

DEV u16 f2bf(float f) {
  u32 u = __builtin_bit_cast(u32, f);
  u += 0x7fffu + ((u >> 16) & 1u);
  return (u16)(u >> 16);
}

DEV void gload_lds16(const void* g, void* l) {
  __builtin_amdgcn_global_load_lds(
      (const __attribute__((address_space(1))) u32*)g,
      (__attribute__((address_space(3))) u32*)l, 16, 0, 0);
}

// ---------------- convert kernels ----------------

__global__ __launch_bounds__(256) void cvt_bf16(const float* __restrict__ in,
                                                u16* __restrict__ out, int n4) {
  int i = blockIdx.x * 256 + threadIdx.x;
  const int stride = gridDim.x * 256;
  for (; i < n4; i += stride) {
    const float4 v = ((const float4*)in)[i];
    ushort4 o;
    o.x = f2bf(v.x); o.y = f2bf(v.y); o.z = f2bf(v.z); o.w = f2bf(v.w);
    ((ushort4*)out)[i] = o;
  }
}

// in [K,N] fp32 -> out [N,K] bf16 (transposed)
__global__ __launch_bounds__(256) void cvtT_bf16(const float* __restrict__ in,
                                                 u16* __restrict__ out, int K, int N) {
  int i = blockIdx.x * 256 + threadIdx.x;
  if (i >= N * K) return;
  int n = i / K, k = i - n * K;
  out[i] = f2bf(in[(long)k * N + n]);
}

// biasM[h][p] = bias_table[rel_idx[p]*12 + h], p < 2401
__global__ __launch_bounds__(256) void bias_pre(const float* __restrict__ bias_table,
                                                const int* __restrict__ rel_idx,
                                                float* __restrict__ biasM) {
  int i = blockIdx.x * 256 + threadIdx.x;
  if (i >= 12 * 2401) return;
  int h = i / 2401, p = i - h * 2401;
  biasM[i] = bias_table[rel_idx[p] * 12 + h];
}

// ---------------- 256x256 deep-pipelined GEMM ----------------
// LDS layout (per 32KB buffer): A = 128 rows x 128B, B at +16384 same.
// Logical (m-row, kblock kb in 0..3; 16B each) -> lds_row = m>>1,
// blk = ((m&1)*4+kb) ^ (lds_row&7), byte = lds_row*128 + blk*16.
// 16-lane read phases then hit each bank-quad exactly 2x (free, m136).
// global_load_lds writes linearly; the per-lane GLOBAL source address
// carries the inverse permutation (both-sides-or-neither, rule #21).
// Schedule: round-2 proven-safe form — all cross-wave frag reads strictly
// after the vmcnt(8)+s_barrier pair (vmcnt is per-wave; only the barrier
// makes other waves' global_load_lds stores visible).
template <bool OUT_BF16>
__global__ __launch_bounds__(512, 2) void gemm256(
    const u16* __restrict__ A, const u16* __restrict__ BT,
    void* __restrict__ C, const float* __restrict__ bias,
    int M, int N, int K, int nbn) {
  __shared__ alignas(16) char lds[131072];
  const int t = threadIdx.x;
  const int w = t >> 6, l = t & 63, lr = l & 15, lhi = l >> 4;
  const int wr = w >> 2, wc = w & 3;

  // bijective XCD-chunked swizzle
  const int nwg = gridDim.x;
  const int q = nwg >> 3, r = nwg & 7;
  const int xcd = blockIdx.x & 7, lid = blockIdx.x >> 3;
  const int swz = (xcd < r ? xcd * (q + 1) : r * (q + 1) + (xcd - r) * q) + lid;
  const int bm = swz / nbn, bn = swz % nbn;

  const int T = K >> 5;  // K-tiles of 32
  const long Kb = (long)K * 2;

  // staging: lane l fills LDS slot (lds_row = base + (l>>3), blk = l&7).
  // unswizzled blk' = (l&7) ^ (l>>3); global m-row = base + 2*(l>>3) + (blk'>>2),
  // col byte = (blk'&3)*16.
  const int unswz = (l & 7) ^ (l >> 3);
  const int arow = 2 * (l >> 3) + (unswz >> 2);
  const int acolb = (unswz & 3) << 4;
  const char* gA0 = (const char*)A + (long)(bm * 256 + w * 32 + arow) * Kb + acolb;
  const char* gA1 = gA0 + 16 * Kb;
  const char* gB0 = (const char*)BT + (long)(bn * 256 + w * 32 + arow) * Kb + acolb;
  const char* gB1 = gB0 + 16 * Kb;
  const int ldA0 = w * 2048, ldA1 = w * 2048 + 1024;
  const int ldB0 = 16384 + w * 2048, ldB1 = 16384 + w * 2048 + 1024;

#define STAGE(tt)                               \
  {                                             \
    const int bb = ((tt) & 3) * 32768;          \
    const long ko = (long)(tt) * 64;            \
    gload_lds16(gA0 + ko, lds + bb + ldA0);     \
    gload_lds16(gA1 + ko, lds + bb + ldA1);     \
    gload_lds16(gB0 + ko, lds + bb + ldB0);     \
    gload_lds16(gB1 + ko, lds + bb + ldB1);     \
  }
#define VMCNT8 asm volatile("s_waitcnt vmcnt(8)" ::: "memory")
#define BAR                                  \
  asm volatile("" ::: "memory");             \
  __builtin_amdgcn_s_barrier();              \
  asm volatile("" ::: "memory")

  // frag read offsets within a buffer: for m = base + mt*16 + lr, kb = lhi:
  // lds_row = base/2 + mt*8 + (lr>>1); blk = ((lr&1)*4 + lhi) ^ (lr>>1).
  const int rblk = ((((lr & 1) << 2) | lhi) ^ (lr >> 1));
  const int aoff0 = (wr * 64 + (lr >> 1)) * 128 + rblk * 16;          // + mt*1024
  const int boff0 = 16384 + (wc * 32 + (lr >> 1)) * 128 + rblk * 16;  // + nt*1024

  f32x4 acc[8][4];
#pragma unroll
  for (int m = 0; m < 8; ++m)
#pragma unroll
    for (int n = 0; n < 4; ++n) acc[m][n] = (f32x4){0.f, 0.f, 0.f, 0.f};
  bf16x8 afr[8], bfr[4];

  // prologue: 3 tiles staged, wait tile 0 (own stores) then barrier (all waves)
  STAGE(0); STAGE(1); STAGE(2);
  VMCNT8;
  BAR;
#pragma unroll
  for (int n = 0; n < 4; ++n) bfr[n] = *(const bf16x8*)(lds + boff0 + n * 1024);
#pragma unroll
  for (int m = 0; m < 4; ++m) afr[m] = *(const bf16x8*)(lds + aoff0 + m * 1024);

  for (int kt = 0; kt < T; ++kt) {
    if (kt + 3 < T) STAGE(kt + 3);
    {
      const int bb = (kt & 3) * 32768;
#pragma unroll
      for (int m = 4; m < 8; ++m)
        afr[m] = *(const bf16x8*)(lds + bb + aoff0 + m * 1024);
    }
    __builtin_amdgcn_s_setprio(1);
#pragma unroll
    for (int m = 0; m < 4; ++m)
#pragma unroll
      for (int n = 0; n < 4; ++n)
        acc[m][n] = __builtin_amdgcn_mfma_f32_16x16x32_bf16(afr[m], bfr[n], acc[m][n], 0, 0, 0);
    __builtin_amdgcn_s_setprio(0);
    __builtin_amdgcn_s_setprio(1);
#pragma unroll
    for (int m = 4; m < 8; ++m)
#pragma unroll
      for (int n = 0; n < 4; ++n)
        acc[m][n] = __builtin_amdgcn_mfma_f32_16x16x32_bf16(afr[m], bfr[n], acc[m][n], 0, 0, 0);
    __builtin_amdgcn_s_setprio(0);
    // tile kt consumed. vmcnt(8): own stores of tile kt+1 landed; barrier:
    // ALL waves reached this point, so all stores of tile kt+1 are visible.
    VMCNT8;
    BAR;
    if (kt + 1 < T) {
      const int bb = ((kt + 1) & 3) * 32768;
#pragma unroll
      for (int n = 0; n < 4; ++n)
        bfr[n] = *(const bf16x8*)(lds + bb + boff0 + n * 1024);
#pragma unroll
      for (int m = 0; m < 4; ++m)
        afr[m] = *(const bf16x8*)(lds + bb + aoff0 + m * 1024);
    }
  }
#undef STAGE
#undef VMCNT8
#undef BAR

  const int row0 = bm * 256 + wr * 128 + 4 * lhi;
  const int col0 = bn * 256 + wc * 64 + lr;
  if (OUT_BF16) {
    u16* Cc = (u16*)C;
#pragma unroll
    for (int m = 0; m < 8; ++m)
#pragma unroll
      for (int rr = 0; rr < 4; ++rr) {
        const long row = row0 + m * 16 + rr;
#pragma unroll
        for (int n = 0; n < 4; ++n)
          Cc[row * N + col0 + n * 16] = f2bf(acc[m][n][rr]);
      }
  } else {
    float* Cf = (float*)C;
    float bv[4];
#pragma unroll
    for (int n = 0; n < 4; ++n) bv[n] = bias[col0 + n * 16];
#pragma unroll
    for (int m = 0; m < 8; ++m)
#pragma unroll
      for (int rr = 0; rr < 4; ++rr) {
        const long row = row0 + m * 16 + rr;
#pragma unroll
        for (int n = 0; n < 4; ++n)
          Cf[row * N + col0 + n * 16] = acc[m][n][rr] + bv[n];
      }
  }
}

// ---------------- fused attention ----------------
__global__ __launch_bounds__(256) void attn_kernel(
    const u16* __restrict__ qkv,        // [B*49, 2304] bf16
    const float* __restrict__ prev,     // [B,12,49,49]
    const float* __restrict__ biasM,    // [12,49*49]
    float* __restrict__ prev_out,       // [B,12,49,49]
    u16* __restrict__ attn_out) {       // [B*49, 768] bf16
  __shared__ u16 Qs[64][72];   // aliased as Ps after QK^T
  __shared__ u16 Ks[64][72];
  __shared__ u16 VTs[64][72];
  __shared__ float SB[2432];   // prev+bias, then scores

  const int bh = blockIdx.x;
  const int b = bh / 12, h = bh % 12;
  const int t = threadIdx.x, w = t >> 6, l = t & 63, lr = l & 15, lhi = l >> 4;

  const u16* base = qkv + (long)(b * 49) * 2304 + h * 64;
  for (int idx = t; idx < 49 * 16; idx += 256) {
    const int n = idx >> 4, c4 = (idx & 15) << 2;
    const u16* rp = base + (long)n * 2304;
    ushort4 qv = *(const ushort4*)(rp + c4);
    ushort4 kv = *(const ushort4*)(rp + 768 + c4);
    ushort4 vv = *(const ushort4*)(rp + 1536 + c4);
    *(ushort4*)&Qs[n][c4] = qv;
    *(ushort4*)&Ks[n][c4] = kv;
    VTs[c4 + 0][n] = vv.x;
    VTs[c4 + 1][n] = vv.y;
    VTs[c4 + 2][n] = vv.z;
    VTs[c4 + 3][n] = vv.w;
  }
  for (int idx = t; idx < 1024; idx += 256) {
    const int j = idx & 15;
    if (j) VTs[idx >> 4][48 + j] = 0;
  }
  {
    const float* pv = prev + (long)bh * 2401;
    const float* bm = biasM + h * 2401;
    for (int i = t; i < 2401; i += 256) SB[i] = pv[i] + bm[i];
  }
  __syncthreads();

  bf16x8 af0 = *(const bf16x8*)&Qs[16 * w + lr][lhi * 8];
  bf16x8 af1 = *(const bf16x8*)&Qs[16 * w + lr][32 + lhi * 8];
  f32x4 sacc[4];
#pragma unroll
  for (int tc = 0; tc < 4; ++tc) {
    sacc[tc] = (f32x4){0.f, 0.f, 0.f, 0.f};
    bf16x8 b0 = *(const bf16x8*)&Ks[16 * tc + lr][lhi * 8];
    bf16x8 b1 = *(const bf16x8*)&Ks[16 * tc + lr][32 + lhi * 8];
    sacc[tc] = __builtin_amdgcn_mfma_f32_16x16x32_bf16(af0, b0, sacc[tc], 0, 0, 0);
    sacc[tc] = __builtin_amdgcn_mfma_f32_16x16x32_bf16(af1, b1, sacc[tc], 0, 0, 0);
  }

  u16 (*Ps)[72] = Qs;
  const int nrow0 = 16 * w + 4 * lhi;
  float rs[4];
#pragma unroll
  for (int r = 0; r < 4; ++r) {
    const int row = nrow0 + r;
    const bool rv = row < 49;
    float sv[4];
#pragma unroll
    for (int tc = 0; tc < 4; ++tc) {
      const int col = 16 * tc + lr;
      const bool valid = rv && (col < 49);
      const int sidx = (row < 49 ? row : 48) * 49 + (col < 49 ? col : 48);
      const float pb = SB[sidx];
      const float s = sacc[tc][r] * 0.125f + pb;
      if (valid) SB[sidx] = s;
      sv[tc] = valid ? s : -INFINITY;
    }
    float mx = fmaxf(fmaxf(sv[0], sv[1]), fmaxf(sv[2], sv[3]));
#pragma unroll
    for (int off = 8; off; off >>= 1) mx = fmaxf(mx, __shfl_xor(mx, off, 16));
    float e[4], sum = 0.f;
#pragma unroll
    for (int tc = 0; tc < 4; ++tc) {
      e[tc] = __expf(sv[tc] - mx);
      sum += e[tc];
    }
#pragma unroll
    for (int off = 8; off; off >>= 1) sum += __shfl_xor(sum, off, 16);
    rs[r] = 1.0f / sum;
#pragma unroll
    for (int tc = 0; tc < 4; ++tc)
      Ps[row][16 * tc + lr] = rv ? f2bf(e[tc]) : (u16)0;
  }
  __syncthreads();

  bf16x8 pf0 = *(const bf16x8*)&Ps[16 * w + lr][lhi * 8];
  bf16x8 pf1 = *(const bf16x8*)&Ps[16 * w + lr][32 + lhi * 8];
  f32x4 oacc[4];
#pragma unroll
  for (int dc = 0; dc < 4; ++dc) {
    oacc[dc] = (f32x4){0.f, 0.f, 0.f, 0.f};
    bf16x8 v0 = *(const bf16x8*)&VTs[16 * dc + lr][lhi * 8];
    bf16x8 v1 = *(const bf16x8*)&VTs[16 * dc + lr][32 + lhi * 8];
    oacc[dc] = __builtin_amdgcn_mfma_f32_16x16x32_bf16(pf0, v0, oacc[dc], 0, 0, 0);
    oacc[dc] = __builtin_amdgcn_mfma_f32_16x16x32_bf16(pf1, v1, oacc[dc], 0, 0, 0);
  }
  u16* ob = attn_out + (long)(b * 49) * 768 + h * 64;
#pragma unroll
  for (int r = 0; r < 4; ++r) {
    const int row = nrow0 + r;
    if (row < 49) {
#pragma unroll
      for (int dc = 0; dc < 4; ++dc)
        ob[(long)row * 768 + 16 * dc + lr] = f2bf(oacc[dc][r] * rs[r]);
    }
  }

  {
    float* pout = prev_out + (long)bh * 2401;
    for (int i = t; i < 2401; i += 256) pout[i] = SB[i];
  }
}

// ---------------- launch ----------------
extern "C" void kernel_launch(void* const* d_in, const int* in_sizes, int n_in,
                              void* d_out, int out_size, void* d_ws, size_t ws_size,
                              hipStream_t stream) {
  const float* x = (const float*)d_in[0];
  const float* prev = (const float*)d_in[1];
  const float* qkv_w = (const float*)d_in[2];
  const float* proj_w = (const float*)d_in[3];
  const float* proj_b = (const float*)d_in[4];
  const float* bias_table = (const float*)d_in[5];
  const int* rel_idx = (const int*)d_in[6];

  const int B = in_sizes[0] / (49 * 768);  // 1024
  const int M = B * 49;                    // 50176 = 196*256

  float* out0 = (float*)d_out;             // [M,768]
  float* out1 = out0 + (size_t)M * 768;    // [B,12,49,49]

  char* ws = (char*)d_ws;
  u16* xbf = (u16*)ws;                                     // M*768 bf16 (reused as attn_out)
  u16* qkvbf = (u16*)(ws + (size_t)M * 768 * 2);           // M*2304 bf16
  u16* qkvwT = (u16*)(ws + (size_t)M * 768 * 2 + (size_t)M * 2304 * 2);  // [2304,768]
  u16* projwT = qkvwT + 2304 * 768;                        // [768,768]
  float* biasM = (float*)(projwT + 768 * 768);             // [12,2401]

  bias_pre<<<(12 * 2401 + 255) / 256, 256, 0, stream>>>(bias_table, rel_idx, biasM);
  cvt_bf16<<<2048, 256, 0, stream>>>(x, xbf, M * 768 / 4);
  cvtT_bf16<<<(2304 * 768 + 255) / 256, 256, 0, stream>>>(qkv_w, qkvwT, 768, 2304);
  cvtT_bf16<<<(768 * 768 + 255) / 256, 256, 0, stream>>>(proj_w, projwT, 768, 768);

  gemm256<true><<<(M / 256) * (2304 / 256), 512, 0, stream>>>(
      xbf, qkvwT, qkvbf, nullptr, M, 2304, 768, 2304 / 256);

  attn_kernel<<<B * 12, 256, 0, stream>>>(qkvbf, prev, biasM, out1, xbf);

  gemm256<false><<<(M / 256) * (768 / 256), 512, 0, stream>>>(
      xbf, projwT, out0, proj_b, M, 768, 768, 768 / 256);
}

// Round 6
// 526.952 us; speedup vs baseline: 1.2365x; 1.0174x over previous
//
#include <hip/hip_runtime.h>

typedef unsigned short u16;
typedef unsigned int u32;
typedef float f32x4 __attribute__((ext_vector_type(4)));
typedef __bf16 bf16x8 __attribute__((ext_vector_type(8)));

#define DEV static __device__ __forceinline__

DEV u16 f2bf(float f) {
  u32 u = __builtin_bit_cast(u32, f);
  u += 0x7fffu + ((u >> 16) & 1u);
  return (u16)(u >> 16);
}

DEV void gload_lds16(const void* g, void* l) {
  __builtin_amdgcn_global_load_lds(
      (const __attribute__((address_space(1))) u32*)g,
      (__attribute__((address_space(3))) u32*)l, 16, 0, 0);
}

// ---------------- convert kernels ----------------

__global__ __launch_bounds__(256) void cvt_bf16(const float* __restrict__ in,
                                                u16* __restrict__ out, int n4) {
  int i = blockIdx.x * 256 + threadIdx.x;
  const int stride = gridDim.x * 256;
  for (; i < n4; i += stride) {
    const float4 v = ((const float4*)in)[i];
    ushort4 o;
    o.x = f2bf(v.x); o.y = f2bf(v.y); o.z = f2bf(v.z); o.w = f2bf(v.w);
    ((ushort4*)out)[i] = o;
  }
}

// in [K,N] fp32 -> out [N,K] bf16 (transposed)
__global__ __launch_bounds__(256) void cvtT_bf16(const float* __restrict__ in,
                                                 u16* __restrict__ out, int K, int N) {
  int i = blockIdx.x * 256 + threadIdx.x;
  if (i >= N * K) return;
  int n = i / K, k = i - n * K;
  out[i] = f2bf(in[(long)k * N + n]);
}

// biasM[h][p] = bias_table[rel_idx[p]*12 + h], p < 2401
__global__ __launch_bounds__(256) void bias_pre(const float* __restrict__ bias_table,
                                                const int* __restrict__ rel_idx,
                                                float* __restrict__ biasM) {
  int i = blockIdx.x * 256 + threadIdx.x;
  if (i >= 12 * 2401) return;
  int h = i / 2401, p = i - h * 2401;
  biasM[i] = bias_table[rel_idx[p] * 12 + h];
}

// ---------------- 256x256 deep-pipelined GEMM ----------------
// LDS layout (per 32KB buffer): A = 128 rows x 128B, B at +16384 same.
// Swizzle: (m-row, kblock kb) -> lds_row = m>>1, blk = ((m&1)*4+kb) ^ (lds_row&7)
// (bank-conflict-free, verified: SQ_LDS_BANK_CONFLICT = 0).
// Schedule: depth-3 staging, vmcnt(4) at bottom so tiles kt+1,kt+2 are
// published at the start of iter kt+1 -> next tile's fragments (bfr,afr[0-3])
// prefetched in-register DURING iter kt (ping-pong X/Y), making the
// post-barrier path start with MFMA immediately.
template <bool OUT_BF16>
__global__ __launch_bounds__(512, 2) void gemm256(
    const u16* __restrict__ A, const u16* __restrict__ BT,
    void* __restrict__ C, const float* __restrict__ bias,
    int M, int N, int K, int nbn) {
  __shared__ alignas(16) char lds[131072];
  const int t = threadIdx.x;
  const int w = t >> 6, l = t & 63, lr = l & 15, lhi = l >> 4;
  const int wr = w >> 2, wc = w & 3;

  // bijective XCD-chunked swizzle
  const int nwg = gridDim.x;
  const int q = nwg >> 3, r = nwg & 7;
  const int xcd = blockIdx.x & 7, lid = blockIdx.x >> 3;
  const int swz = (xcd < r ? xcd * (q + 1) : r * (q + 1) + (xcd - r) * q) + lid;
  const int bm = swz / nbn, bn = swz % nbn;

  const int T = K >> 5;  // K-tiles of 32 (K=768 -> 24, even)
  const long Kb = (long)K * 2;

  // staging source (inverse swizzle; global_load_lds dest is linear)
  const int unswz = (l & 7) ^ (l >> 3);
  const int arow = 2 * (l >> 3) + (unswz >> 2);
  const int acolb = (unswz & 3) << 4;
  const char* gA0 = (const char*)A + (long)(bm * 256 + w * 32 + arow) * Kb + acolb;
  const char* gA1 = gA0 + 16 * Kb;
  const char* gB0 = (const char*)BT + (long)(bn * 256 + w * 32 + arow) * Kb + acolb;
  const char* gB1 = gB0 + 16 * Kb;
  const int ldA0 = w * 2048, ldA1 = w * 2048 + 1024;
  const int ldB0 = 16384 + w * 2048, ldB1 = 16384 + w * 2048 + 1024;

#define STAGE(tt)                               \
  {                                             \
    const int bb = ((tt) & 3) * 32768;          \
    const long ko = (long)(tt) * 64;            \
    gload_lds16(gA0 + ko, lds + bb + ldA0);     \
    gload_lds16(gA1 + ko, lds + bb + ldA1);     \
    gload_lds16(gB0 + ko, lds + bb + ldB0);     \
    gload_lds16(gB1 + ko, lds + bb + ldB1);     \
  }
#define BAR                                  \
  asm volatile("" ::: "memory");             \
  __builtin_amdgcn_s_barrier();              \
  asm volatile("" ::: "memory")

  // frag read offsets (swizzled)
  const int rblk = ((((lr & 1) << 2) | lhi) ^ (lr >> 1));
  const int aoff0 = (wr * 64 + (lr >> 1)) * 128 + rblk * 16;          // + mt*1024
  const int boff0 = 16384 + (wc * 32 + (lr >> 1)) * 128 + rblk * 16;  // + nt*1024

  f32x4 acc[8][4];
#pragma unroll
  for (int m = 0; m < 8; ++m)
#pragma unroll
    for (int n = 0; n < 4; ++n) acc[m][n] = (f32x4){0.f, 0.f, 0.f, 0.f};
  bf16x8 afrX[4], bfrX[4], afrY[4], bfrY[4];

#define CLUSTER1(S)                                                        \
  __builtin_amdgcn_s_setprio(1);                                           \
  _Pragma("unroll") for (int m = 0; m < 4; ++m)                            \
      _Pragma("unroll") for (int n = 0; n < 4; ++n)                        \
          acc[m][n] = __builtin_amdgcn_mfma_f32_16x16x32_bf16(             \
              afr##S[m], bfr##S[n], acc[m][n], 0, 0, 0);                   \
  __builtin_amdgcn_s_setprio(0)
#define CLUSTER2(S)                                                        \
  __builtin_amdgcn_s_setprio(1);                                           \
  _Pragma("unroll") for (int m = 0; m < 4; ++m)                            \
      _Pragma("unroll") for (int n = 0; n < 4; ++n)                        \
          acc[m + 4][n] = __builtin_amdgcn_mfma_f32_16x16x32_bf16(         \
              afr2[m], bfr##S[n], acc[m + 4][n], 0, 0, 0);                 \
  __builtin_amdgcn_s_setprio(0)

// Iter kt (set S current, R next): tiles kt and kt+1 are published at entry.
// afr2 = A-half2 of tile kt (short-lived); prefetch next tile's B then A1.
#define BODY(kt, S, R)                                                     \
  {                                                                        \
    if ((kt) + 3 < T) STAGE((kt) + 3);                                     \
    const int bbc = ((kt) & 3) * 32768;                                    \
    const int nx = ((kt) + 1 < T) ? (kt) + 1 : (kt);                       \
    const int bbn = (nx & 3) * 32768;                                      \
    bf16x8 afr2[4];                                                        \
    _Pragma("unroll") for (int m = 0; m < 4; ++m)                          \
        afr2[m] = *(const bf16x8*)(lds + bbc + aoff0 + (m + 4) * 1024);    \
    CLUSTER1(S);                                                           \
    _Pragma("unroll") for (int n = 0; n < 4; ++n)                          \
        bfr##R[n] = *(const bf16x8*)(lds + bbn + boff0 + n * 1024);        \
    CLUSTER2(S);                                                           \
    _Pragma("unroll") for (int m = 0; m < 4; ++m)                          \
        afr##R[m] = *(const bf16x8*)(lds + bbn + aoff0 + m * 1024);        \
    if ((kt) + 3 < T) {                                                    \
      asm volatile("s_waitcnt vmcnt(4)" ::: "memory");                     \
    } else {                                                               \
      asm volatile("s_waitcnt vmcnt(0)" ::: "memory");                     \
    }                                                                      \
    BAR;                                                                   \
  }

  // prologue: stage 0,1,2; vmcnt(4) -> tiles 0,1 landed; barrier publishes.
  STAGE(0); STAGE(1); STAGE(2);
  asm volatile("s_waitcnt vmcnt(4)" ::: "memory");
  BAR;
#pragma unroll
  for (int n = 0; n < 4; ++n) bfrX[n] = *(const bf16x8*)(lds + boff0 + n * 1024);
#pragma unroll
  for (int m = 0; m < 4; ++m) afrX[m] = *(const bf16x8*)(lds + aoff0 + m * 1024);

  for (int i = 0; i < T / 2; ++i) {
    BODY(2 * i, X, Y);
    BODY(2 * i + 1, Y, X);
  }
#undef STAGE
#undef BAR
#undef CLUSTER1
#undef CLUSTER2
#undef BODY

  const int row0 = bm * 256 + wr * 128 + 4 * lhi;
  const int col0 = bn * 256 + wc * 64 + lr;
  if (OUT_BF16) {
    u16* Cc = (u16*)C;
#pragma unroll
    for (int m = 0; m < 8; ++m)
#pragma unroll
      for (int rr = 0; rr < 4; ++rr) {
        const long row = row0 + m * 16 + rr;
#pragma unroll
        for (int n = 0; n < 4; ++n)
          Cc[row * N + col0 + n * 16] = f2bf(acc[m][n][rr]);
      }
  } else {
    float* Cf = (float*)C;
    float bv[4];
#pragma unroll
    for (int n = 0; n < 4; ++n) bv[n] = bias[col0 + n * 16];
#pragma unroll
    for (int m = 0; m < 8; ++m)
#pragma unroll
      for (int rr = 0; rr < 4; ++rr) {
        const long row = row0 + m * 16 + rr;
#pragma unroll
        for (int n = 0; n < 4; ++n)
          Cf[row * N + col0 + n * 16] = acc[m][n][rr] + bv[n];
      }
  }
}

// ---------------- fused attention ----------------
__global__ __launch_bounds__(256) void attn_kernel(
    const u16* __restrict__ qkv,        // [B*49, 2304] bf16
    const float* __restrict__ prev,     // [B,12,49,49]
    const float* __restrict__ biasM,    // [12,49*49]
    float* __restrict__ prev_out,       // [B,12,49,49]
    u16* __restrict__ attn_out) {       // [B*49, 768] bf16
  __shared__ u16 Qs[64][72];   // aliased as Ps after QK^T
  __shared__ u16 Ks[64][72];
  __shared__ u16 VTs[64][72];
  __shared__ float SB[2432];   // prev+bias, then scores

  const int bh = blockIdx.x;
  const int b = bh / 12, h = bh % 12;
  const int t = threadIdx.x, w = t >> 6, l = t & 63, lr = l & 15, lhi = l >> 4;

  const u16* base = qkv + (long)(b * 49) * 2304 + h * 64;
  for (int idx = t; idx < 49 * 16; idx += 256) {
    const int n = idx >> 4, c4 = (idx & 15) << 2;
    const u16* rp = base + (long)n * 2304;
    ushort4 qv = *(const ushort4*)(rp + c4);
    ushort4 kv = *(const ushort4*)(rp + 768 + c4);
    ushort4 vv = *(const ushort4*)(rp + 1536 + c4);
    *(ushort4*)&Qs[n][c4] = qv;
    *(ushort4*)&Ks[n][c4] = kv;
    VTs[c4 + 0][n] = vv.x;
    VTs[c4 + 1][n] = vv.y;
    VTs[c4 + 2][n] = vv.z;
    VTs[c4 + 3][n] = vv.w;
  }
  for (int idx = t; idx < 1024; idx += 256) {
    const int j = idx & 15;
    if (j) VTs[idx >> 4][48 + j] = 0;
  }
  {
    const float* pv = prev + (long)bh * 2401;
    const float* bm = biasM + h * 2401;
    for (int i = t; i < 2401; i += 256) SB[i] = pv[i] + bm[i];
  }
  __syncthreads();

  bf16x8 af0 = *(const bf16x8*)&Qs[16 * w + lr][lhi * 8];
  bf16x8 af1 = *(const bf16x8*)&Qs[16 * w + lr][32 + lhi * 8];
  f32x4 sacc[4];
#pragma unroll
  for (int tc = 0; tc < 4; ++tc) {
    sacc[tc] = (f32x4){0.f, 0.f, 0.f, 0.f};
    bf16x8 b0 = *(const bf16x8*)&Ks[16 * tc + lr][lhi * 8];
    bf16x8 b1 = *(const bf16x8*)&Ks[16 * tc + lr][32 + lhi * 8];
    sacc[tc] = __builtin_amdgcn_mfma_f32_16x16x32_bf16(af0, b0, sacc[tc], 0, 0, 0);
    sacc[tc] = __builtin_amdgcn_mfma_f32_16x16x32_bf16(af1, b1, sacc[tc], 0, 0, 0);
  }

  u16 (*Ps)[72] = Qs;
  const int nrow0 = 16 * w + 4 * lhi;
  float rs[4];
#pragma unroll
  for (int r = 0; r < 4; ++r) {
    const int row = nrow0 + r;
    const bool rv = row < 49;
    float sv[4];
#pragma unroll
    for (int tc = 0; tc < 4; ++tc) {
      const int col = 16 * tc + lr;
      const bool valid = rv && (col < 49);
      const int sidx = (row < 49 ? row : 48) * 49 + (col < 49 ? col : 48);
      const float pb = SB[sidx];
      const float s = sacc[tc][r] * 0.125f + pb;
      if (valid) SB[sidx] = s;
      sv[tc] = valid ? s : -INFINITY;
    }
    float mx = fmaxf(fmaxf(sv[0], sv[1]), fmaxf(sv[2], sv[3]));
#pragma unroll
    for (int off = 8; off; off >>= 1) mx = fmaxf(mx, __shfl_xor(mx, off, 16));
    float e[4], sum = 0.f;
#pragma unroll
    for (int tc = 0; tc < 4; ++tc) {
      e[tc] = __expf(sv[tc] - mx);
      sum += e[tc];
    }
#pragma unroll
    for (int off = 8; off; off >>= 1) sum += __shfl_xor(sum, off, 16);
    rs[r] = 1.0f / sum;
#pragma unroll
    for (int tc = 0; tc < 4; ++tc)
      Ps[row][16 * tc + lr] = rv ? f2bf(e[tc]) : (u16)0;
  }
  __syncthreads();

  bf16x8 pf0 = *(const bf16x8*)&Ps[16 * w + lr][lhi * 8];
  bf16x8 pf1 = *(const bf16x8*)&Ps[16 * w + lr][32 + lhi * 8];
  f32x4 oacc[4];
#pragma unroll
  for (int dc = 0; dc < 4; ++dc) {
    oacc[dc] = (f32x4){0.f, 0.f, 0.f, 0.f};
    bf16x8 v0 = *(const bf16x8*)&VTs[16 * dc + lr][lhi * 8];
    bf16x8 v1 = *(const bf16x8*)&VTs[16 * dc + lr][32 + lhi * 8];
    oacc[dc] = __builtin_amdgcn_mfma_f32_16x16x32_bf16(pf0, v0, oacc[dc], 0, 0, 0);
    oacc[dc] = __builtin_amdgcn_mfma_f32_16x16x32_bf16(pf1, v1, oacc[dc], 0, 0, 0);
  }
  u16* ob = attn_out + (long)(b * 49) * 768 + h * 64;
#pragma unroll
  for (int r = 0; r < 4; ++r) {
    const int row = nrow0 + r;
    if (row < 49) {
#pragma unroll
      for (int dc = 0; dc < 4; ++dc)
        ob[(long)row * 768 + 16 * dc + lr] = f2bf(oacc[dc][r] * rs[r]);
    }
  }

  {
    float* pout = prev_out + (long)bh * 2401;
    for (int i = t; i < 2401; i += 256) pout[i] = SB[i];
  }
}

// ---------------- launch ----------------
extern "C" void kernel_launch(void* const* d_in, const int* in_sizes, int n_in,
                              void* d_out, int out_size, void* d_ws, size_t ws_size,
                              hipStream_t stream) {
  const float* x = (const float*)d_in[0];
  const float* prev = (const float*)d_in[1];
  const float* qkv_w = (const float*)d_in[2];
  const float* proj_w = (const float*)d_in[3];
  const float* proj_b = (const float*)d_in[4];
  const float* bias_table = (const float*)d_in[5];
  const int* rel_idx = (const int*)d_in[6];

  const int B = in_sizes[0] / (49 * 768);  // 1024
  const int M = B * 49;                    // 50176 = 196*256

  float* out0 = (float*)d_out;             // [M,768]
  float* out1 = out0 + (size_t)M * 768;    // [B,12,49,49]

  char* ws = (char*)d_ws;
  u16* xbf = (u16*)ws;                                     // M*768 bf16 (reused as attn_out)
  u16* qkvbf = (u16*)(ws + (size_t)M * 768 * 2);           // M*2304 bf16
  u16* qkvwT = (u16*)(ws + (size_t)M * 768 * 2 + (size_t)M * 2304 * 2);  // [2304,768]
  u16* projwT = qkvwT + 2304 * 768;                        // [768,768]
  float* biasM = (float*)(projwT + 768 * 768);             // [12,2401]

  bias_pre<<<(12 * 2401 + 255) / 256, 256, 0, stream>>>(bias_table, rel_idx, biasM);
  cvt_bf16<<<2048, 256, 0, stream>>>(x, xbf, M * 768 / 4);
  cvtT_bf16<<<(2304 * 768 + 255) / 256, 256, 0, stream>>>(qkv_w, qkvwT, 768, 2304);
  cvtT_bf16<<<(768 * 768 + 255) / 256, 256, 0, stream>>>(proj_w, projwT, 768, 768);

  gemm256<true><<<(M / 256) * (2304 / 256), 512, 0, stream>>>(
      xbf, qkvwT, qkvbf, nullptr, M, 2304, 768, 2304 / 256);

  attn_kernel<<<B * 12, 256, 0, stream>>>(qkvbf, prev, biasM, out1, xbf);

  gemm256<false><<<(M / 256) * (768 / 256), 512, 0, stream>>>(
      xbf, projwT, out0, proj_b, M, 768, 768, 768 / 256);
}